// Round 1
// 178.772 us; speedup vs baseline: 1.2219x; 1.2219x over previous
//
#include <hip/hip_runtime.h>
#include <math.h>

// DCT2net, R6: two kernels, lane = (col, kj) coordinate, barrier-free main loop.
//
// R6 changes vs R5 (theory: k2 VALU-bound at 75% busy with lgkm-wait bubbles):
//  - c1 DCT matrix baked as compile-time literals (constexpr cos) -> no kernarg
//    s_loads in the loop, coefficients ride as VOP2 fmac inline literals.
//  - u^64 via trans pipe: exp2(64*log2|u|) instead of 6-mul chain.
//  - pnz 16-lane reduction via DPP row_ror (VALU pipe) instead of ds_swizzle.
//  - fold: w folded into accumulate fmaf, 13 pre-scale muls dropped.
//
// K2 (dct2net_k2): per lane-group of 16 (13 kj used), one patch column.
//   Streams image rows down a 61-output-row segment:
//     hDCT (x via ds_bpermute from 16 loader lanes) -> 13-reg ring Rv
//     vDCT + shrink (even/odd symmetry) -> tn[13], pnz
//     w = 1/(1+sum nz) via 4-step DPP row_ror rotate-reduce within the 16-group
//     vertical inverse-DCT fold (scaled by w) -> 13-reg ring Hr
//     retire H row -> global Hg[img][a][col][16], w -> Wg[img][row][col]
//   NO __syncthreads in the loop; no cross-wave traffic at all.
// K3 (dct2net_k3): per out row: U[c][dy] = sum_j c1[dy][j] H[a][c][j] (169 FMA),
//   out = sum_dy U[b+12-dy][dy] / (13x13 box-sum of w). Same-wave LDS only.
//
// ws layout: Hg = 2*488*512*16 f32 (31.98 MB), Wg = 2*512*512 f32 (2 MB). ~34 MB.

#define P13    13
#define IMGW   512
#define OUTW   488
#define SEGH   61      // H rows per K2 segment; 8*61 = 488 exact
#define NSEG   8
#define HCOLS  512     // padded col dim of Hg
#define HPITCH 16      // padded j dim of Hg

struct C1mat { float v[P13 * P13]; };  // v[x*13+k] = sqrt(2/13)*Ci[k]*cos((2x+1)k*pi/26)

// ---- compile-time DCT table (values identical to the old host-side double math) ----
constexpr double kPI = 3.14159265358979323846264338327950288;

constexpr double ccos_pm_pi(double th) {   // Taylor, valid |th| <= pi (3e-18 tail)
    double term = 1.0, s = 1.0;
    const double th2 = th * th;
    for (int n = 1; n <= 25; ++n) {
        term *= -th2 / (double)((2 * n - 1) * (2 * n));
        s += term;
    }
    return s;
}
constexpr double csqrt(double v) {
    double x = (v > 1.0) ? v : 1.0;
    for (int i = 0; i < 64; ++i) x = 0.5 * (x + v / x);
    return x;
}
constexpr C1mat make_c1() {
    C1mat m{};
    const double s213 = csqrt(2.0 / 13.0);
    const double is2  = 1.0 / csqrt(2.0);
    for (int x = 0; x < P13; ++x)
        for (int k = 0; k < P13; ++k) {
            // (2x+1)k*pi/26 reduced mod 2*pi exactly via integer mod 52
            int mm = ((2 * x + 1) * k) % 52;
            double th = (mm <= 26) ? (mm * kPI / 26.0) : ((mm - 52) * kPI / 26.0);
            double Ci = (k == 0) ? is2 : 1.0;
            m.v[x * P13 + k] = (float)(s213 * Ci * ccos_pm_pi(th));
        }
    return m;
}
__device__ constexpr C1mat c1c = make_c1();

// rotate-reduce add within each 16-lane DPP row (our col group): N in {1,2,4,8}
#define ROR16_ADD(v, N)                                                        \
    v += __int_as_float(__builtin_amdgcn_mov_dpp(__float_as_int(v),            \
                                                 0x120 + (N), 0xF, 0xF, true))

__device__ __forceinline__ void vdct_shrink(const float (&Rv)[P13],
                                            float inv3s, float (&tn)[P13], float& pnz)
{
    float Se[6], So[6];
#pragma unroll
    for (int k = 0; k < 6; ++k) { Se[k] = Rv[k] + Rv[12 - k]; So[k] = Rv[k] - Rv[12 - k]; }
#pragma unroll
    for (int i = 0; i < P13; ++i) {
        float t;
        if ((i & 1) == 0) {
            t = c1c.v[6 * P13 + i] * Rv[6];
#pragma unroll
            for (int k = 0; k < 6; ++k) t = fmaf(c1c.v[k * P13 + i], Se[k], t);
        } else {
            t = c1c.v[0 * P13 + i] * So[0];
#pragma unroll
            for (int k = 1; k < 6; ++k) t = fmaf(c1c.v[k * P13 + i], So[k], t);
        }
        float u = t * inv3s;
        u = __builtin_amdgcn_fmed3f(u, -1.3f, 1.3f);   // clamp: u^64 <= 2e7, nz err ~5e-8
        // u^64 on the trans pipe: exp2(64*log2|u|). log(0) = -inf -> exp2 -> 0: correct.
        float lg  = __builtin_amdgcn_logf(fabsf(u));
        float p64 = __builtin_amdgcn_exp2f(64.0f * lg);
        float nz  = p64 * __builtin_amdgcn_rcpf(p64 + 1.0f);
        pnz += nz;
        tn[i] = t * nz;
    }
}

__device__ __forceinline__ void fold_vert(const float (&tn)[P13], float w1, float (&H)[P13])
{
#pragma unroll
    for (int dx = 0; dx < 6; ++dx) {
        float E = c1c.v[dx * P13 + 0] * tn[0];
#pragma unroll
        for (int i = 2; i < P13; i += 2) E = fmaf(c1c.v[dx * P13 + i], tn[i], E);
        float O = c1c.v[dx * P13 + 1] * tn[1];
#pragma unroll
        for (int i = 3; i < P13; i += 2) O = fmaf(c1c.v[dx * P13 + i], tn[i], O);
        H[dx]      = fmaf(w1, E + O, H[dx]);
        H[12 - dx] = fmaf(w1, E - O, H[12 - dx]);
    }
    float z6 = c1c.v[6 * P13 + 0] * tn[0];
#pragma unroll
    for (int i = 2; i < P13; i += 2) z6 = fmaf(c1c.v[6 * P13 + i], tn[i], z6);
    H[6] = fmaf(w1, z6, H[6]);
}

__global__ __launch_bounds__(256) void dct2net_k2(
    const float* __restrict__ xg, const float* __restrict__ sigmag,
    float* __restrict__ Hg, float* __restrict__ Wg)
{
    __shared__ float c1lds[169];
    const int tid = threadIdx.x;
    if (tid < 169) c1lds[tid] = c1c.v[tid];
    __syncthreads();                       // once, for the c1 table only

    const int lane = tid & 63;
    const int wv   = tid >> 6;             // wave 0..3
    const int g    = lane >> 4;            // col group 0..3 within wave
    const int jj   = lane & 15;            // kj (0..12 used, 13..15 idle)
    const int img  = blockIdx.z;
    const int hs   = blockIdx.y * SEGH;    // first H row of this segment
    const int cbw  = blockIdx.x * 16 + wv * 4;   // wave's first col
    const int col  = cbw + g;              // this lane's patch column (0..511)

    const float inv3s = 1.0f / (3.0f * sigmag[0]);
    const float* xin  = xg + (size_t)img * IMGW * IMGW;

    // per-lane c1 column for the hDCT (j = jj), from the LDS table
    float c1col[P13];
    {
        const int jc = (jj < 13) ? jj : 12;
#pragma unroll
        for (int y = 0; y < P13; ++y) c1col[y] = c1lds[y * P13 + jc];
    }

    float Rv[P13], Hr[P13];
#pragma unroll
    for (int k = 0; k < P13; ++k) { Rv[k] = 0.0f; Hr[k] = 0.0f; }

    int xcol = cbw + lane; xcol = (xcol < IMGW - 1) ? xcol : (IMGW - 1);
    float xv = 0.0f;
    if (lane < 16) xv = xin[(size_t)hs * IMGW + xcol];   // row hs, cols cbw..cbw+15

    // steps k=0..84: load/hDCT row hs+k; k>=12: patch row hs+k-12; k>=24: H row hs+k-24
    for (int k = 0; k <= 84; ++k) {
        // gather this wave's 16 staged x values via bpermute (sliding 13-window)
        float xw[P13];
#pragma unroll
        for (int y = 0; y < P13; ++y)
            xw[y] = __int_as_float(
                __builtin_amdgcn_ds_bpermute(4 * (g + y), __float_as_int(xv)));
        {   // prefetch next row (consumed next iteration -> latency hidden)
            int nr = hs + k + 1; nr = (nr < IMGW) ? nr : (IMGW - 1);
            if (lane < 16) xv = xin[(size_t)nr * IMGW + xcol];
        }
        // hDCT: two partial FMA chains
        float a0 = c1col[0] * xw[0], a1 = c1col[1] * xw[1];
#pragma unroll
        for (int y = 2; y < P13; y += 2) a0 = fmaf(c1col[y], xw[y], a0);
#pragma unroll
        for (int y = 3; y < P13; y += 2) a1 = fmaf(c1col[y], xw[y], a1);
#pragma unroll
        for (int q = 0; q < P13 - 1; ++q) Rv[q] = Rv[q + 1];
        Rv[P13 - 1] = a0 + a1;

        if (k >= 12) {
            const int ph = hs + k - 12;    // patch row (<= 499 by construction)
            float tn[P13]; float pnz = 0.0f;
            vdct_shrink(Rv, inv3s, tn, pnz);
            if (jj >= 13) pnz = 0.0f;      // idle lanes contribute 0
            // 16-lane rotate-reduce on the VALU pipe: every lane gets sum of 13 pnz
            ROR16_ADD(pnz, 1);
            ROR16_ADD(pnz, 2);
            ROR16_ADD(pnz, 4);
            ROR16_ADD(pnz, 8);
            const float w = __builtin_amdgcn_rcpf(1.0f + pnz);
            if (jj == 0) Wg[((size_t)img * IMGW + ph) * IMGW + col] = w;
            fold_vert(tn, w, Hr);
            if (k >= 24) {                 // H row a complete (folds from rows a..a+12)
                const int a = hs + k - 24;
                Hg[(((size_t)img * OUTW + a) * HCOLS + col) * HPITCH + jj] = Hr[0];
            }
#pragma unroll
            for (int q = 0; q < P13 - 1; ++q) Hr[q] = Hr[q + 1];
            Hr[P13 - 1] = 0.0f;
        }
    }
}

__global__ __launch_bounds__(256) void dct2net_k3(
    const float* __restrict__ Hg, const float* __restrict__ Wg,
    float* __restrict__ outg)
{
    __shared__ float U[4][76][14];   // stride 14: 2-way bank alias only (free)
    __shared__ float vw[4][80];
    const int tid  = threadIdx.x;
    const int lane = tid & 63;
    const int wv   = tid >> 6;
    const int img  = blockIdx.z;
    const int a    = blockIdx.y * 4 + wv;      // out row (<= 487)
    const int cb   = blockIdx.x * 64;          // out col base

    // build U[c][dy] and vw[c] for c in [cb, cb+76): 64 lanes + 12-lane halo pass
#pragma unroll
    for (int h = 0; h < 2; ++h) {
        const int li = lane + 64 * h;
        if (h == 0 || lane < 12) {
            int c = cb + li; c = (c < 499) ? c : 499;   // clamp; clamped slots unused
            const float* hp = &Hg[(((size_t)img * OUTW + a) * HCOLS + c) * HPITCH];
            float hv[P13];
            *(float4*)&hv[0] = *(const float4*)hp;
            *(float4*)&hv[4] = *(const float4*)(hp + 4);
            *(float4*)&hv[8] = *(const float4*)(hp + 8);
            hv[12] = hp[12];
#pragma unroll
            for (int dy = 0; dy < P13; ++dy) {
                float s0 = c1c.v[dy * P13 + 0] * hv[0];
                float s1 = c1c.v[dy * P13 + 1] * hv[1];
#pragma unroll
                for (int j = 2; j < P13; j += 2) s0 = fmaf(c1c.v[dy * P13 + j], hv[j], s0);
#pragma unroll
                for (int j = 3; j < P13; j += 2) s1 = fmaf(c1c.v[dy * P13 + j], hv[j], s1);
                U[wv][li][dy] = s0 + s1;
            }
            float s = 0.0f;
            const float* wp = &Wg[((size_t)img * IMGW + a) * IMGW + c];
#pragma unroll
            for (int dx = 0; dx < P13; ++dx) s += wp[dx * IMGW];
            vw[wv][li] = s;
        }
    }
    // same-wave LDS write->read: program order, no barrier needed
    float num = 0.0f;
#pragma unroll
    for (int dy = 0; dy < P13; ++dy) num += U[wv][lane + 12 - dy][dy];
    float den = 0.0f;
#pragma unroll
    for (int d = 0; d < P13; ++d) den += vw[wv][lane + d];
    const int ow = cb + lane;
    if (ow < OUTW)
        outg[((size_t)img * OUTW + a) * OUTW + ow] = num * __builtin_amdgcn_rcpf(den);
}

extern "C" void kernel_launch(void* const* d_in, const int* in_sizes, int n_in,
                              void* d_out, int out_size, void* d_ws, size_t ws_size,
                              hipStream_t stream)
{
    const float* x     = (const float*)d_in[0];
    const float* sigma = (const float*)d_in[1];
    float* out = (float*)d_out;

    // ws: Hg (2*488*512*16 f32 = 31.98 MB) then Wg (2*512*512 f32 = 2 MB)
    float* Hg = (float*)d_ws;
    float* Wg = Hg + (size_t)2 * OUTW * HCOLS * HPITCH;

    dct2net_k2<<<dim3(32, NSEG, 2), 256, 0, stream>>>(x, sigma, Hg, Wg);
    dct2net_k3<<<dim3(8, 122, 2), 256, 0, stream>>>(Hg, Wg, out);
}